// Round 5
// baseline (888.641 us; speedup 1.0000x reference)
//
#include <hip/hip_runtime.h>
#include <stdint.h>

#define NN 8192
#define K_ORD 262144u      // ordered top-k positions (off-diagonal, both triangles)
#define CAND_CAP 4194304u  // candidate buffer cap (32MB of ws; expected ~1e3 used)
#define CLS_CAP 2048u      // threshold-bin class cap (expected ~2-64)
#define NBLK_MASK 16384u   // dim3(2, NN) x 256
#define NBLK_RND 512u

typedef float f32x4 __attribute__((ext_vector_type(4)));

// ws layout (uint32 words):
// [0..255]     round-1 per-probe counts (device atomicAdd; zeroed by sort blk0)
// [256..511]   round-2 per-probe counts            [512..1023] pad (zeroed)
// [4096] hi  [4097] lo  [4098] r_ord  [4099] cand_cnt
// [4100] done1  [4101] done2  [4102] done3(mask)  [4103] pad   (all zeroed)
// [4104..12295] sorted p values (8192 floats, desc by key)
// [12296..]    candidate entries: packed u64 {key(lo32), flat_idx(hi32)}
#define WS_HI 4096
#define WS_LO 4097
#define WS_R 4098
#define WS_TIECNT 4099
#define WS_D1 4100
#define WS_D2 4101
#define WS_D3 4102
#define WS_STATE0 4096
#define WS_STATEN 8
#define WS_SORT 4104
#define WS_TIE 12296

__device__ __forceinline__ uint32_t fkey(float x) {
    // order-preserving map float -> uint32 (neg: ~u, pos: u|0x80000000)
    uint32_t u = __float_as_uint(x);
    uint32_t m = (uint32_t)((int32_t)u >> 31) | 0x80000000u;
    return u ^ m;
}
__device__ __forceinline__ float inv_fkey(uint32_t k) {
    uint32_t u = (k & 0x80000000u) ? (k ^ 0x80000000u) : ~k;
    return __uint_as_float(u);
}

// ---------------------------------------------------------------------------
// Kernel A (R4-verbatim): brute-force rank sort (desc by key, ties by index).
// 1024 blocks x 256 thr; block ranks 8 elements; b128 LDS scan.
__global__ void __launch_bounds__(256) sort_kernel(const float* __restrict__ p,
                                                   uint32_t* __restrict__ ws) {
    __shared__ uint32_t ks[NN];
    const int tx = threadIdx.x;
    if (blockIdx.x == 0) {
        for (int t = tx; t < 1024; t += 256) ws[t] = 0u;       // probe count slots
        if (tx < WS_STATEN) ws[WS_STATE0 + tx] = 0u;           // state + done ctrs
    }
    for (int t = tx; t < NN / 4; t += 256) {
        const float4 v = reinterpret_cast<const float4*>(p)[t];
        reinterpret_cast<uint4*>(ks)[t] =
            make_uint4(fkey(v.x), fkey(v.y), fkey(v.z), fkey(v.w));
    }
    __syncthreads();
    const int e = blockIdx.x * 8 + (tx >> 5);
    const int seg = tx & 31;
    const uint32_t ke = ks[e];
    const uint4* k4 = reinterpret_cast<const uint4*>(ks);
    uint32_t cnt = 0;
    for (int it = 0; it < 64; ++it) {
        const int t4 = seg + 32 * it;     // lanes read consecutive 16B: conflict-free
        const uint4 kj = k4[t4];
        const int j = t4 * 4;
        cnt += (kj.x > ke) ? 1u : 0u; cnt += (kj.x == ke && (j + 0) < e) ? 1u : 0u;
        cnt += (kj.y > ke) ? 1u : 0u; cnt += (kj.y == ke && (j + 1) < e) ? 1u : 0u;
        cnt += (kj.z > ke) ? 1u : 0u; cnt += (kj.z == ke && (j + 2) < e) ? 1u : 0u;
        cnt += (kj.w > ke) ? 1u : 0u; cnt += (kj.w == ke && (j + 3) < e) ? 1u : 0u;
    }
    for (int off = 16; off > 0; off >>= 1) cnt += __shfl_down(cnt, off, 32);
    if (seg == 0)
        reinterpret_cast<float*>(ws + WS_SORT)[cnt] = inv_fkey(ke);  // unique rank
}

// ---------------------------------------------------------------------------
// Partial f(T) over rows [a0, a0+2048): 4 INDEPENDENT interleaved 14-step
// chains per thread (ILP4; R6/R9/R13-proven, branchless — gallop variant was
// +12us from divergence; large-stride probes are LDS broadcasts = free).
__device__ uint32_t eval_count4(const float* __restrict__ ps, uint32_t T, int a0) {
    const int a = a0 + threadIdx.x * 4;
    float pa[4];
    uint32_t neg[4];
    int pos[4] = {0, 0, 0, 0};
#pragma unroll
    for (int c = 0; c < 4; ++c) {
        pa[c] = ps[a + c];
        neg[c] = __float_as_uint(pa[c]) >> 31;
    }
#pragma unroll
    for (int st = NN; st > 0; st >>= 1) {
#pragma unroll
        for (int c = 0; c < 4; ++c) {
            const int cand = pos[c] + st;
            if (cand <= NN) {
                const uint32_t pr = (fkey(pa[c] * ps[cand - 1]) > T) ? 1u : 0u;
                if (pr ^ neg[c]) pos[c] = cand;
            }
        }
    }
    uint32_t cnt = 0;
#pragma unroll
    for (int c = 0; c < 4; ++c) {
        uint32_t cc = neg[c] ? (uint32_t)(NN - pos[c]) : (uint32_t)pos[c];
        cc -= (fkey(pa[c] * pa[c]) > T) ? 1u : 0u;   // exclude diagonal pairing
        cnt += cc;
    }
    return cnt;
}

// Bracket from `rounds` completed rounds (R3-proven wave-shfl form).
// On exit: T* in [lo,hi], fstar = f(hi) < K.
template <int NT>
__device__ void bracket_chain(const uint32_t* __restrict__ ws, int rounds,
                              uint32_t* __restrict__ sh,
                              uint32_t& lo, uint32_t& hi, uint32_t& fstar) {
    const int tx = threadIdx.x;
    lo = 0u; hi = 0xFFFFFFFFu; fstar = 0u;
    for (int r = 0; r < rounds; ++r) {
        uint32_t flag = 1024u;
        if (tx < 256) {
            const uint32_t c = __hip_atomic_load(&ws[r * 256 + tx], __ATOMIC_RELAXED,
                                                 __HIP_MEMORY_SCOPE_AGENT);
            if (c < K_ORD) flag = (uint32_t)tx;
        }
#pragma unroll
        for (int off = 32; off > 0; off >>= 1) {
            const uint32_t o = __shfl_down(flag, off, 64);
            flag = flag < o ? flag : o;
        }
        if ((tx & 63) == 0) sh[tx >> 6] = flag;
        __syncthreads();
        const uint32_t cs = min(min(sh[0], sh[1]), min(sh[2], sh[3]));
        __syncthreads();
        fstar = __hip_atomic_load(&ws[r * 256 + cs], __ATOMIC_RELAXED,
                                  __HIP_MEMORY_SCOPE_AGENT);
        const uint64_t W = (uint64_t)(hi - lo);
        const uint32_t Tc = lo + (uint32_t)(((uint64_t)(cs + 1) * W) >> 8);
        if (cs > 0) lo = lo + (uint32_t)(((uint64_t)cs * W) >> 8) + 1u;
        hi = Tc;
    }
}

// Bounded acquire-spin on a done counter (agent scope; bypasses stale L2).
// Cap makes a logic bug fail the check instead of hanging the queue.
__device__ __forceinline__ void spin_done(uint32_t* __restrict__ ws, int word,
                                          uint32_t target) {
    for (long it = 0; it < (1L << 24); ++it) {
        if (__hip_atomic_load(&ws[word], __ATOMIC_ACQUIRE,
                              __HIP_MEMORY_SCOPE_AGENT) >= target) return;
        __builtin_amdgcn_s_sleep(2);
    }
}

// ---------------------------------------------------------------------------
// Kernel B: rounds 1+2+finalize fused. Cooperative launch (co-residency
// guarantee only — NO cg::grid.sync: R1 measured ~28us/sync; one-way flags
// pay last-writer latency instead). 512 blocks x 512 thr; block bx covers
// probe=bx>>1, halves (bx&1)*4096 + {0,2048} (R1-fused layout, proven).
__global__ void __launch_bounds__(512) rounds12_kernel(uint32_t* __restrict__ ws) {
    __shared__ float ps[NN];
    __shared__ uint32_t sh[8];
    const int tx = threadIdx.x;
    const int bx = blockIdx.x;
    for (int t = tx; t < NN / 4; t += 512)
        reinterpret_cast<float4*>(ps)[t] =
            reinterpret_cast<const float4*>(ws + WS_SORT)[t];   // pre-boundary data: plain loads ok
    __syncthreads();
    const int probe = bx >> 1;
    const int a0 = (bx & 1) * 4096;

    // ---- round 1: T from the full [0, 2^32) split ----
    {
        const uint32_t T = (uint32_t)(((uint64_t)(probe + 1) * 0xFFFFFFFFull) >> 8);
        uint32_t v = eval_count4(ps, T, a0) + eval_count4(ps, T, a0 + 2048);
#pragma unroll
        for (int off = 32; off > 0; off >>= 1) v += __shfl_down(v, off, 64);
        if ((tx & 63) == 0) sh[tx >> 6] = v;
        __syncthreads();
        if (tx == 0) {
            uint32_t s = 0;
#pragma unroll
            for (int w = 0; w < 8; ++w) s += sh[w];
            atomicAdd(&ws[probe], s);                       // device-scope RMW (m20)
            __hip_atomic_fetch_add(&ws[WS_D1], 1u, __ATOMIC_RELEASE,
                                   __HIP_MEMORY_SCOPE_AGENT);
        }
        __syncthreads();   // protect sh before bracket_chain reuse
    }
    // ---- wait for all 512 round-1 partials, then local bracket ----
    if (tx == 0) spin_done(ws, WS_D1, NBLK_RND);
    __syncthreads();
    uint32_t lo, hi, fs;
    bracket_chain<512>(ws, 1, sh, lo, hi, fs);

    // ---- round 2 ----
    {
        const uint64_t W = (uint64_t)(hi - lo);
        const uint32_t T = lo + (uint32_t)(((uint64_t)(probe + 1) * W) >> 8);
        uint32_t v = eval_count4(ps, T, a0) + eval_count4(ps, T, a0 + 2048);
#pragma unroll
        for (int off = 32; off > 0; off >>= 1) v += __shfl_down(v, off, 64);
        if ((tx & 63) == 0) sh[tx >> 6] = v;
        __syncthreads();
        if (tx == 0) {
            uint32_t s = 0;
#pragma unroll
            for (int w = 0; w < 8; ++w) s += sh[w];
            atomicAdd(&ws[256 + probe], s);
            __hip_atomic_fetch_add(&ws[WS_D2], 1u, __ATOMIC_RELEASE,
                                   __HIP_MEMORY_SCOPE_AGENT);
        }
        __syncthreads();
    }
    // ---- finalize (block 0 only): hi/lo/r via plain stores (boundary flushes) ----
    if (bx != 0) return;
    if (tx == 0) spin_done(ws, WS_D2, NBLK_RND);
    __syncthreads();
    bracket_chain<512>(ws, 2, sh, lo, hi, fs);
    if (tx == 0) {
        ws[WS_HI] = hi;               // f(hi) < K
        ws[WS_LO] = lo;               // f(lo-1) >= K  (K-th key in [lo,hi])
        ws[WS_R] = K_ORD - fs;        // in-bracket slots, by (key desc, idx asc)
    }
}

// ---------------------------------------------------------------------------
// Kernel C: streamed 268MB mask write (NT float4 stores) + tail-block-fused
// final radix select. Candidates cross XCDs within this kernel -> packed u64
// agent-scope stores/loads (per-XCD L2 non-coherent; agent ops hit the
// coherence point). Last block (done-ctr) runs the R4-proven select inline.
__global__ void __launch_bounds__(256) mask_kernel(const float* __restrict__ p,
                                                   float* __restrict__ out,
                                                   uint32_t* __restrict__ ws) {
    __shared__ uint32_t hist[2048];
    __shared__ unsigned long long cls[CLS_CAP];
    __shared__ uint32_t clsn, sdone, sb, srp, wtot[4];
    const int tx = threadIdx.x;
    const int i = blockIdx.y;
    const int jb0 = blockIdx.x * 4096;
    const uint32_t hi = ws[WS_HI];     // pre-boundary data: plain loads ok
    const uint32_t lo = ws[WS_LO];
    const float pi = p[i];
    const size_t rowbase = (size_t)i * NN;
    unsigned long long* buf = reinterpret_cast<unsigned long long*>(ws + WS_TIE);
#pragma unroll
    for (int q = 0; q < 4; ++q) {
        const int j = jb0 + q * 1024 + tx * 4;
        const float4 pj = *reinterpret_cast<const float4*>(p + j);
        const float pjv[4] = {pj.x, pj.y, pj.z, pj.w};
        float vv[4];
#pragma unroll
        for (int c = 0; c < 4; ++c) {
            const int jj = j + c;
            float v = 0.0f;
            if (jj != i) {
                const uint32_t key = fkey(pi * pjv[c]);
                if (key > hi) {
                    v = 1.0f;
                } else if (key >= lo) {
                    const uint32_t pos = atomicAdd(&ws[WS_TIECNT], 1u);
                    if (pos < CAND_CAP) {
                        const unsigned long long pk =
                            (unsigned long long)key |
                            ((unsigned long long)(uint32_t)(i * NN + jj) << 32);
                        __hip_atomic_store(&buf[pos], pk, __ATOMIC_RELAXED,
                                           __HIP_MEMORY_SCOPE_AGENT);
                    }
                }
            }
            vv[c] = v;
        }
        f32x4 o;
        o.x = vv[0]; o.y = vv[1]; o.z = vv[2]; o.w = vv[3];
        __builtin_nontemporal_store(o,
            reinterpret_cast<f32x4*>(out + rowbase + j));
    }
    // ---- completion protocol: last block runs the final select ----
    __syncthreads();                   // all stores drained (vmcnt) before RMW
    if (tx == 0) {
        sdone = __hip_atomic_fetch_add(&ws[WS_D3], 1u, __ATOMIC_ACQ_REL,
                                       __HIP_MEMORY_SCOPE_AGENT);
    }
    __syncthreads();
    if (sdone != NBLK_MASK - 1u) return;

    // ===== tail block: single-block radix select over the n candidates =====
    // Bracket width hi-lo <= 65535 after 2 rounds, so (key-lo)>>5 indexes
    // 2048 exact 32-key bins. Top r by (key desc, idx asc).
    uint32_t n = __hip_atomic_load(&ws[WS_TIECNT], __ATOMIC_RELAXED,
                                   __HIP_MEMORY_SCOPE_AGENT);
    if (n > CAND_CAP) n = CAND_CAP;
    const uint32_t r = ws[WS_R];       // >= 1, <= n (f(lo-1) >= K)
    for (int t = tx; t < 2048; t += 256) hist[t] = 0u;
    if (tx == 0) { clsn = 0u; sb = 0u; srp = 0u; }
    __syncthreads();
    for (uint32_t e = tx; e < n; e += 256) {
        const unsigned long long v = __hip_atomic_load(&buf[e], __ATOMIC_RELAXED,
                                                       __HIP_MEMORY_SCOPE_AGENT);
        atomicAdd(&hist[((uint32_t)v - lo) >> 5], 1u);
    }
    __syncthreads();
    // Per-thread 8-bin slab [tx*8, tx*8+8); suffix-sum across threads.
    uint32_t own = 0;
    uint32_t h[8];
#pragma unroll
    for (int j = 0; j < 8; ++j) { h[j] = hist[tx * 8 + j]; own += h[j]; }
    uint32_t s = own;
    const int lane = tx & 63;
#pragma unroll
    for (int off = 1; off < 64; off <<= 1) {
        const uint32_t o = __shfl_down(s, off, 64);
        s += (lane + off < 64) ? o : 0u;
    }
    if (lane == 0) wtot[tx >> 6] = s;     // wave suffix at lane0 == wave total
    __syncthreads();
    uint32_t tail = 0;
    for (int w = (tx >> 6) + 1; w < 4; ++w) tail += wtot[w];
    const uint32_t S = s + tail;          // sum of slabs >= tx (incl. own)
    uint32_t acc = S - own;               // suffix strictly beyond own slab
#pragma unroll
    for (int j = 7; j >= 0; --j) {
        const uint32_t nacc = acc + h[j];
        if (nacc >= r && acc < r) { sb = (uint32_t)(tx * 8 + j); srp = r - acc; }
        acc = nacc;
    }
    __syncthreads();
    const uint32_t bstar = sb, rp = srp;
    // pass: bins above bstar -> 1.0; bin == bstar -> class list
    for (uint32_t e = tx; e < n; e += 256) {
        const unsigned long long v = __hip_atomic_load(&buf[e], __ATOMIC_RELAXED,
                                                       __HIP_MEMORY_SCOPE_AGENT);
        const uint32_t b = ((uint32_t)v - lo) >> 5;
        if (b > bstar) {
            out[(uint32_t)(v >> 32)] = 1.0f;
        } else if (b == bstar) {
            const uint32_t posi = atomicAdd(&clsn, 1u);
            if (posi < CLS_CAP) cls[posi] = v;
        }
    }
    __syncthreads();
    uint32_t m = clsn;
    if (m > CLS_CAP) m = CLS_CAP;
    for (uint32_t e = tx; e < m; e += 256) {
        const unsigned long long me = cls[e];
        const uint32_t mk = (uint32_t)me, mi = (uint32_t)(me >> 32);
        uint32_t rank = 0;
        for (uint32_t q = 0; q < m; ++q) {
            const unsigned long long o = cls[q];
            const uint32_t ok = (uint32_t)o, oi = (uint32_t)(o >> 32);
            rank += ((ok > mk) || (ok == mk && oi < mi)) ? 1u : 0u;
        }
        if (rank < rp) out[mi] = 1.0f;
    }
}

extern "C" void kernel_launch(void* const* d_in, const int* in_sizes, int n_in,
                              void* d_out, int out_size, void* d_ws, size_t ws_size,
                              hipStream_t stream) {
    const float* p = (const float*)d_in[0];
    float* out = (float*)d_out;
    uint32_t* ws = (uint32_t*)d_ws;

    sort_kernel<<<1024, 256, 0, stream>>>(p, ws);
    void* args[1] = {(void*)&ws};
    (void)hipLaunchCooperativeKernel(
        reinterpret_cast<const void*>(&rounds12_kernel), dim3(NBLK_RND),
        dim3(512), args, 0u, stream);
    mask_kernel<<<dim3(2, NN), 256, 0, stream>>>(p, out, ws);
}

// Round 6
// 325.538 us; speedup vs baseline: 2.7298x; 2.7298x over previous
//
#include <hip/hip_runtime.h>
#include <stdint.h>

#define NN 8192
#define K_ORD 262144u      // ordered top-k positions (off-diagonal, both triangles)
#define TIE_CAP 16384u

typedef float f32x4 __attribute__((ext_vector_type(4)));

// ws layout (uint32 words):
// [0..767]     per-probe counts: round r (0..2) probe c -> ws[r*256 + c].
//              4 quarter-blocks atomicAdd into the slot (device-scope);
//              slots zeroed by sort_kernel block 0. [768..1023] pad (zeroed).
// [4096..4103] state: [4099] tie_cnt, rest legacy/pad (zeroed by sort)
// [4104..12295] sorted p values (8192 floats, desc by key)
// [12296..]    tie entries: uint2 {key, flat_idx} (12296 even -> 8B aligned)
#define WS_TIECNT 4099
#define WS_STATE0 4096
#define WS_STATEN 8
#define WS_SORT 4104
#define WS_TIE 12296

__device__ __forceinline__ uint32_t fkey(float x) {
    // order-preserving map float -> uint32 (neg: ~u, pos: u|0x80000000)
    uint32_t u = __float_as_uint(x);
    uint32_t m = (uint32_t)((int32_t)u >> 31) | 0x80000000u;
    return u ^ m;
}
__device__ __forceinline__ float inv_fkey(uint32_t k) {
    uint32_t u = (k & 0x80000000u) ? (k ^ 0x80000000u) : ~k;
    return __uint_as_float(u);
}

// ---------------------------------------------------------------------------
// Kernel 1: brute-force rank sort of p (desc by key, ties by index) -> ws.
// 1024 blocks x 256 thr; block ranks 8 elements. Scan via ds_read_b128
// (uint4 = 4 keys/read: 256 b32 iters -> 64 b128 iters, ~3 cyc/key vs 6).
__global__ void __launch_bounds__(256) sort_kernel(const float* __restrict__ p,
                                                   uint32_t* __restrict__ ws) {
    __shared__ uint32_t ks[NN];
    const int tx = threadIdx.x;
    if (blockIdx.x == 0) {
        for (int t = tx; t < 1024; t += 256) ws[t] = 0u;       // probe count slots
        if (tx < WS_STATEN) ws[WS_STATE0 + tx] = 0u;           // state (tie_cnt)
    }
    for (int t = tx; t < NN / 4; t += 256) {
        const float4 v = reinterpret_cast<const float4*>(p)[t];
        reinterpret_cast<uint4*>(ks)[t] =
            make_uint4(fkey(v.x), fkey(v.y), fkey(v.z), fkey(v.w));
    }
    __syncthreads();
    const int e = blockIdx.x * 8 + (tx >> 5);
    const int seg = tx & 31;
    const uint32_t ke = ks[e];
    const uint4* k4 = reinterpret_cast<const uint4*>(ks);
    uint32_t cnt = 0;
    for (int it = 0; it < 64; ++it) {
        const int t4 = seg + 32 * it;     // lanes read consecutive 16B: conflict-free
        const uint4 kj = k4[t4];
        const int j = t4 * 4;
        cnt += (kj.x > ke) ? 1u : 0u; cnt += (kj.x == ke && (j + 0) < e) ? 1u : 0u;
        cnt += (kj.y > ke) ? 1u : 0u; cnt += (kj.y == ke && (j + 1) < e) ? 1u : 0u;
        cnt += (kj.z > ke) ? 1u : 0u; cnt += (kj.z == ke && (j + 2) < e) ? 1u : 0u;
        cnt += (kj.w > ke) ? 1u : 0u; cnt += (kj.w == ke && (j + 3) < e) ? 1u : 0u;
    }
    for (int off = 16; off > 0; off >>= 1) cnt += __shfl_down(cnt, off, 32);
    if (seg == 0)
        reinterpret_cast<float*>(ws + WS_SORT)[cnt] = inv_fkey(ke);  // unique rank
}

// ---------------------------------------------------------------------------
// Partial f(T) over rows [a0, a0+2048): 4 INDEPENDENT interleaved 14-step
// chains per thread (ILP4; R6/R9/R13-proven, branchless — R2's gallop variant
// was +12us from divergence; large-stride probes are LDS broadcasts = free).
__device__ uint32_t eval_count4(const float* __restrict__ ps, uint32_t T, int a0) {
    const int a = a0 + threadIdx.x * 4;
    float pa[4];
    uint32_t neg[4];
    int pos[4] = {0, 0, 0, 0};
#pragma unroll
    for (int c = 0; c < 4; ++c) {
        pa[c] = ps[a + c];
        neg[c] = __float_as_uint(pa[c]) >> 31;
    }
#pragma unroll
    for (int st = NN; st > 0; st >>= 1) {
#pragma unroll
        for (int c = 0; c < 4; ++c) {
            const int cand = pos[c] + st;
            if (cand <= NN) {
                const uint32_t pr = (fkey(pa[c] * ps[cand - 1]) > T) ? 1u : 0u;
                if (pr ^ neg[c]) pos[c] = cand;
            }
        }
    }
    uint32_t cnt = 0;
#pragma unroll
    for (int c = 0; c < 4; ++c) {
        uint32_t cc = neg[c] ? (uint32_t)(NN - pos[c]) : (uint32_t)pos[c];
        cc -= (fkey(pa[c] * pa[c]) > T) ? 1u : 0u;   // exclude diagonal pairing
        cnt += cc;
    }
    return cnt;
}

// Recompute bracket after `rounds` completed rounds. Per-probe count is ONE
// word (quarters atomicAdd'ed it). Wave-shfl min-reduce: 2 barriers/round
// instead of ~11. sh needs only 8 words. On exit: T* in [lo,hi], fstar=f(hi)<K.
template <int NT>
__device__ void bracket_chain(const uint32_t* __restrict__ ws, int rounds,
                              uint32_t* __restrict__ sh,
                              uint32_t& lo, uint32_t& hi, uint32_t& fstar) {
    const int tx = threadIdx.x;
    lo = 0u; hi = 0xFFFFFFFFu; fstar = 0u;
    for (int r = 0; r < rounds; ++r) {
        uint32_t flag = 1024u;
        if (tx < 256) {
            const uint32_t c = __hip_atomic_load(&ws[r * 256 + tx], __ATOMIC_RELAXED,
                                                 __HIP_MEMORY_SCOPE_AGENT);
            if (c < K_ORD) flag = (uint32_t)tx;
        }
#pragma unroll
        for (int off = 32; off > 0; off >>= 1) {
            const uint32_t o = __shfl_down(flag, off, 64);
            flag = flag < o ? flag : o;
        }
        if ((tx & 63) == 0) sh[tx >> 6] = flag;
        __syncthreads();
        // only waves 0..3 hold tx<256; higher waves wrote 1024 (ignored)
        const uint32_t cs = min(min(sh[0], sh[1]), min(sh[2], sh[3]));
        __syncthreads();   // protect sh before reuse (next round / caller)
        fstar = __hip_atomic_load(&ws[r * 256 + cs], __ATOMIC_RELAXED,
                                  __HIP_MEMORY_SCOPE_AGENT);
        const uint64_t W = (uint64_t)(hi - lo);
        const uint32_t Tc = lo + (uint32_t)(((uint64_t)(cs + 1) * W) >> 8);
        if (cs > 0) lo = lo + (uint32_t)(((uint64_t)cs * W) >> 8) + 1u;
        hi = Tc;
    }
}

// Kernels 2-4: rounds 1-3. Wave-shfl sum-reduce (1 barrier vs 9); partial
// accumulated into the probe's single slot via device-scope atomicAdd.
template <int ROUND>
__global__ void __launch_bounds__(512) select_round_kernel(uint32_t* __restrict__ ws) {
    __shared__ float ps[NN];
    __shared__ uint32_t sh[8];
    const int tx = threadIdx.x;
    const int bx = blockIdx.x;
    for (int t = tx; t < NN / 4; t += 512)
        reinterpret_cast<float4*>(ps)[t] =
            reinterpret_cast<const float4*>(ws + WS_SORT)[t];
    __syncthreads();
    uint32_t lo, hi, fs;
    bracket_chain<512>(ws, ROUND - 1, sh, lo, hi, fs);
    const uint64_t W = (uint64_t)(hi - lo);
    const uint32_t T = lo + (uint32_t)(((uint64_t)((bx >> 2) + 1) * W) >> 8);
    uint32_t v = eval_count4(ps, T, (bx & 3) * 2048);
#pragma unroll
    for (int off = 32; off > 0; off >>= 1) v += __shfl_down(v, off, 64);
    if ((tx & 63) == 0) sh[tx >> 6] = v;
    __syncthreads();
    if (tx == 0) {
        uint32_t s = 0;
#pragma unroll
        for (int w = 0; w < 8; ++w) s += sh[w];
        atomicAdd(&ws[(ROUND - 1) * 256 + (bx >> 2)], s);  // device-scope (m20)
    }
}

// Kernel 5: streamed 268MB mask write, nontemporal float4 stores. Bracket is
// recomputed per block from the compacted partials (3KB L2-resident reads,
// hidden under store BW) — finalize kernel eliminated.
__global__ void __launch_bounds__(256) mask_kernel(const float* __restrict__ p,
                                                   float* __restrict__ out,
                                                   uint32_t* __restrict__ ws) {
    __shared__ uint32_t sh[8];
    uint32_t lo, hi, fs;
    bracket_chain<256>(ws, 3, sh, lo, hi, fs);
    const int tx = threadIdx.x;
    const int i = blockIdx.y;
    const int jb0 = blockIdx.x * 4096;
    const float pi = p[i];
    const size_t rowbase = (size_t)i * NN;
#pragma unroll
    for (int q = 0; q < 4; ++q) {
        const int j = jb0 + q * 1024 + tx * 4;
        const float4 pj = *reinterpret_cast<const float4*>(p + j);
        const float pjv[4] = {pj.x, pj.y, pj.z, pj.w};
        float vv[4];
#pragma unroll
        for (int c = 0; c < 4; ++c) {
            const int jj = j + c;
            float v = 0.0f;
            if (jj != i) {
                const uint32_t key = fkey(pi * pjv[c]);
                if (key > hi) {
                    v = 1.0f;
                } else if (key >= lo) {
                    const uint32_t pos = atomicAdd(&ws[WS_TIECNT], 1u);
                    if (pos < TIE_CAP)
                        reinterpret_cast<uint2*>(ws + WS_TIE)[pos] =
                            make_uint2(key, (uint32_t)(i * NN + jj));
                }
            }
            vv[c] = v;
        }
        f32x4 o;
        o.x = vv[0]; o.y = vv[1]; o.z = vv[2]; o.w = vv[3];
        __builtin_nontemporal_store(o,
            reinterpret_cast<f32x4*>(out + rowbase + j));
    }
}

// Kernel 6: among the n in-bracket entries set the top r by (key desc, flat
// idx asc) to 1.0 — exactly jax.lax.top_k's ordering. Bracket recomputed
// in-block (finalize eliminated); r = K - f(hi).
__global__ void __launch_bounds__(256) tie_select_kernel(float* __restrict__ out,
                                                         uint32_t* __restrict__ ws) {
    __shared__ uint32_t sh[8];
    uint32_t lo, hi, fs;
    bracket_chain<256>(ws, 3, sh, lo, hi, fs);
    const uint32_t r = K_ORD - fs;
    uint32_t n = ws[WS_TIECNT];
    if (n > TIE_CAP) n = TIE_CAP;
    const uint2* buf = reinterpret_cast<const uint2*>(ws + WS_TIE);
    for (uint32_t e = threadIdx.x; e < n; e += 256) {
        const uint2 me = buf[e];
        uint32_t rank = 0;
        for (uint32_t m = 0; m < n; ++m) {
            const uint2 o = buf[m];
            rank += ((o.x > me.x) || (o.x == me.x && o.y < me.y)) ? 1u : 0u;
        }
        if (rank < r) out[me.y] = 1.0f;
    }
}

extern "C" void kernel_launch(void* const* d_in, const int* in_sizes, int n_in,
                              void* d_out, int out_size, void* d_ws, size_t ws_size,
                              hipStream_t stream) {
    const float* p = (const float*)d_in[0];
    float* out = (float*)d_out;
    uint32_t* ws = (uint32_t*)d_ws;

    sort_kernel<<<1024, 256, 0, stream>>>(p, ws);
    select_round_kernel<1><<<1024, 512, 0, stream>>>(ws);
    select_round_kernel<2><<<1024, 512, 0, stream>>>(ws);
    select_round_kernel<3><<<1024, 512, 0, stream>>>(ws);
    mask_kernel<<<dim3(2, NN), 256, 0, stream>>>(p, out, ws);
    tie_select_kernel<<<1, 256, 0, stream>>>(out, ws);
}